// Round 1
// baseline (571.009 us; speedup 1.0000x reference)
//
#include <hip/hip_runtime.h>

typedef unsigned short u16;
typedef unsigned int u32;
typedef u16 us8 __attribute__((ext_vector_type(8)));
typedef __bf16 bf16x8 __attribute__((ext_vector_type(8)));
typedef float f32x4 __attribute__((ext_vector_type(4)));

constexpr int kE = 8;
constexpr int kHID = 2048;    // K of GEMM1, N of GEMM2
constexpr int kINTER = 1408;  // N of GEMM1, K of GEMM2
constexpr int kTOT = 8192;

// fp32 -> bf16 round-to-nearest-even
static __device__ __forceinline__ u16 f2bf(float f) {
  u32 u = __float_as_uint(f);
  u32 r = (u + 0x7fffu + ((u >> 16) & 1u)) >> 16;
  return (u16)r;
}

// async global->LDS, 16B per lane; LDS dest = wave-uniform base + lane*16
static __device__ __forceinline__ void gll16(const u16* g, u16* l) {
  __builtin_amdgcn_global_load_lds(
      (const __attribute__((address_space(1))) u32*)g,
      (__attribute__((address_space(3))) u32*)l, 16, 0, 0);
}

// ---------------- pre-pass: X fp32 -> bf16 ----------------
__global__ void conv_bf16(const float* __restrict__ x, u16* __restrict__ o) {
  size_t i = ((size_t)blockIdx.x * 256 + threadIdx.x) * 8;
  const float4* p = (const float4*)(x + i);
  float4 f0 = p[0], f1 = p[1];
  us8 v;
  v[0] = f2bf(f0.x); v[1] = f2bf(f0.y); v[2] = f2bf(f0.z); v[3] = f2bf(f0.w);
  v[4] = f2bf(f1.x); v[5] = f2bf(f1.y); v[6] = f2bf(f1.z); v[7] = f2bf(f1.w);
  *(us8*)(o + i) = v;
}

// ---------------- pre-pass: W[e][K][N] fp32 -> Wt[e][N][K] bf16 ----------------
// 64x64 tiles through LDS; both K and N are multiples of 64 here.
__global__ void transp_bf16(const float* __restrict__ w, u16* __restrict__ wt,
                            int K, int N) {
  __shared__ float tile[64][65];  // +1 pad: conflict-free column reads
  int e = blockIdx.z;
  const float* we = w + (size_t)e * K * N;
  u16* wte = wt + (size_t)e * K * N;
  int n0 = blockIdx.x * 64, k0 = blockIdx.y * 64;
  int t = threadIdx.x;
  int kl = t >> 4, n4 = (t & 15) * 4;
#pragma unroll
  for (int r = 0; r < 4; r++) {
    int k = r * 16 + kl;
    float4 v = *(const float4*)(we + (size_t)(k0 + k) * N + n0 + n4);
    tile[k][n4 + 0] = v.x; tile[k][n4 + 1] = v.y;
    tile[k][n4 + 2] = v.z; tile[k][n4 + 3] = v.w;
  }
  __syncthreads();
#pragma unroll
  for (int r = 0; r < 2; r++) {
    int c = r * 256 + t;
    int n = c >> 3, kc = (c & 7) * 8;
    us8 o;
#pragma unroll
    for (int j = 0; j < 8; j++) o[j] = f2bf(tile[kc + j][n]);
    *(us8*)(wte + (size_t)(n0 + n) * K + k0 + kc) = o;
  }
}

// -------- expert lookup: flat m-tile -> (expert, row start, row end) --------
static __device__ __forceinline__ bool expert_of_tile(
    const int* __restrict__ tpe, int ty, int& e, int& m0, int& m_end) {
  int tile_base = 0, row_base = 0;
  e = -1;
  for (int i = 0; i < kE; i++) {
    int tc = tpe[i];
    int nt = (tc + 127) >> 7;
    if (e < 0 && ty < tile_base + nt) {
      e = i;
      m0 = row_base + (ty - tile_base) * 128;
      m_end = row_base + tc;
    }
    tile_base += nt;
    row_base += tc;
  }
  return e >= 0;
}

// ---------------- GEMM1: gate+up fused, epilogue silu(g)*u*prob -> h bf16 ----------------
// 128x128 tile, BK=32, 4 waves (2x2 of 64x64), 16x16x32 bf16 MFMA.
__launch_bounds__(256, 2)
__global__ void gemm1(const u16* __restrict__ Xb, const u16* __restrict__ Wgt,
                      const u16* __restrict__ Wut, const float* __restrict__ probs,
                      const int* __restrict__ tpe, u16* __restrict__ H) {
  __shared__ __align__(16) u16 As[128 * 32];
  __shared__ __align__(16) u16 Bgs[128 * 32];
  __shared__ __align__(16) u16 Bus[128 * 32];

  int e, m0, m_end;
  if (!expert_of_tile(tpe, blockIdx.y, e, m0, m_end)) return;
  int n0 = blockIdx.x * 128;

  int t = threadIdx.x;
  int w = t >> 6, lane = t & 63;
  int quad = lane >> 4, l15 = lane & 15;
  int wm = (w >> 1) * 64, wn = (w & 1) * 64;

  // staging: chunk c in [0,512): A-tile row = c>>2 (64B rows), kc = c&3 (16B each)
  int ar0 = m0 + (t >> 2);      if (ar0 > kTOT - 1) ar0 = kTOT - 1;
  int ar1 = m0 + 64 + (t >> 2); if (ar1 > kTOT - 1) ar1 = kTOT - 1;
  const u16* gA0 = Xb + (size_t)ar0 * kHID + (t & 3) * 8;
  const u16* gA1 = Xb + (size_t)ar1 * kHID + (t & 3) * 8;
  size_t wbase = ((size_t)e * kINTER + n0 + (t >> 2)) * kHID + (t & 3) * 8;
  const u16* gBg0 = Wgt + wbase;
  const u16* gBg1 = gBg0 + (size_t)64 * kHID;
  const u16* gBu0 = Wut + wbase;
  const u16* gBu1 = gBu0 + (size_t)64 * kHID;
  u16* lA0 = As + (size_t)(w * 64) * 8;
  u16* lA1 = As + (size_t)(256 + w * 64) * 8;
  u16* lBg0 = Bgs + (size_t)(w * 64) * 8;
  u16* lBg1 = Bgs + (size_t)(256 + w * 64) * 8;
  u16* lBu0 = Bus + (size_t)(w * 64) * 8;
  u16* lBu1 = Bus + (size_t)(256 + w * 64) * 8;

  int aoff[4], boff[4];
#pragma unroll
  for (int i = 0; i < 4; i++) aoff[i] = (wm + i * 16 + l15) * 32 + quad * 8;
#pragma unroll
  for (int j = 0; j < 4; j++) boff[j] = (wn + j * 16 + l15) * 32 + quad * 8;

  f32x4 accg[4][4] = {};
  f32x4 accu[4][4] = {};

  for (int kt = 0; kt < kHID / 32; kt++) {
    gll16(gA0, lA0);  gll16(gA1, lA1);
    gll16(gBg0, lBg0); gll16(gBg1, lBg1);
    gll16(gBu0, lBu0); gll16(gBu1, lBu1);
    gA0 += 32; gA1 += 32; gBg0 += 32; gBg1 += 32; gBu0 += 32; gBu1 += 32;
    __syncthreads();  // drains vmcnt before barrier

    bf16x8 a[4], bg[4], bu[4];
#pragma unroll
    for (int i = 0; i < 4; i++) a[i] = *(const bf16x8*)(As + aoff[i]);
#pragma unroll
    for (int j = 0; j < 4; j++) {
      bg[j] = *(const bf16x8*)(Bgs + boff[j]);
      bu[j] = *(const bf16x8*)(Bus + boff[j]);
    }
#pragma unroll
    for (int i = 0; i < 4; i++)
#pragma unroll
      for (int j = 0; j < 4; j++) {
        accg[i][j] = __builtin_amdgcn_mfma_f32_16x16x32_bf16(a[i], bg[j], accg[i][j], 0, 0, 0);
        accu[i][j] = __builtin_amdgcn_mfma_f32_16x16x32_bf16(a[i], bu[j], accu[i][j], 0, 0, 0);
      }
    __syncthreads();
  }

  // epilogue: h = silu(gate)*up*prob[row], bf16. C/D layout: col=lane&15, row=quad*4+reg
#pragma unroll
  for (int i = 0; i < 4; i++) {
#pragma unroll
    for (int r = 0; r < 4; r++) {
      int row = m0 + wm + i * 16 + quad * 4 + r;
      if (row < m_end) {
        float p = probs[row];
#pragma unroll
        for (int j = 0; j < 4; j++) {
          int col = n0 + wn + j * 16 + l15;
          float g = accg[i][j][r], u = accu[i][j][r];
          float s = g / (1.0f + __expf(-g));
          H[(size_t)row * kINTER + col] = f2bf(s * u * p);
        }
      }
    }
  }
}

// ---------------- GEMM2: out = h @ w_down (probs already folded into h) ----------------
__launch_bounds__(256, 2)
__global__ void gemm2(const u16* __restrict__ H, const u16* __restrict__ Wdt,
                      const int* __restrict__ tpe, float* __restrict__ out) {
  __shared__ __align__(16) u16 As[128 * 32];
  __shared__ __align__(16) u16 Bs[128 * 32];

  int e, m0, m_end;
  if (!expert_of_tile(tpe, blockIdx.y, e, m0, m_end)) return;
  int n0 = blockIdx.x * 128;

  int t = threadIdx.x;
  int w = t >> 6, lane = t & 63;
  int quad = lane >> 4, l15 = lane & 15;
  int wm = (w >> 1) * 64, wn = (w & 1) * 64;

  int ar0 = m0 + (t >> 2);      if (ar0 > kTOT - 1) ar0 = kTOT - 1;
  int ar1 = m0 + 64 + (t >> 2); if (ar1 > kTOT - 1) ar1 = kTOT - 1;
  const u16* gA0 = H + (size_t)ar0 * kINTER + (t & 3) * 8;
  const u16* gA1 = H + (size_t)ar1 * kINTER + (t & 3) * 8;
  const u16* gB0 = Wdt + ((size_t)e * kHID + n0 + (t >> 2)) * kINTER + (t & 3) * 8;
  const u16* gB1 = gB0 + (size_t)64 * kINTER;
  u16* lA0 = As + (size_t)(w * 64) * 8;
  u16* lA1 = As + (size_t)(256 + w * 64) * 8;
  u16* lB0 = Bs + (size_t)(w * 64) * 8;
  u16* lB1 = Bs + (size_t)(256 + w * 64) * 8;

  int aoff[4], boff[4];
#pragma unroll
  for (int i = 0; i < 4; i++) aoff[i] = (wm + i * 16 + l15) * 32 + quad * 8;
#pragma unroll
  for (int j = 0; j < 4; j++) boff[j] = (wn + j * 16 + l15) * 32 + quad * 8;

  f32x4 acc[4][4] = {};

  for (int kt = 0; kt < kINTER / 32; kt++) {
    gll16(gA0, lA0); gll16(gA1, lA1);
    gll16(gB0, lB0); gll16(gB1, lB1);
    gA0 += 32; gA1 += 32; gB0 += 32; gB1 += 32;
    __syncthreads();

    bf16x8 a[4], b[4];
#pragma unroll
    for (int i = 0; i < 4; i++) a[i] = *(const bf16x8*)(As + aoff[i]);
#pragma unroll
    for (int j = 0; j < 4; j++) b[j] = *(const bf16x8*)(Bs + boff[j]);
#pragma unroll
    for (int i = 0; i < 4; i++)
#pragma unroll
      for (int j = 0; j < 4; j++)
        acc[i][j] = __builtin_amdgcn_mfma_f32_16x16x32_bf16(a[i], b[j], acc[i][j], 0, 0, 0);
    __syncthreads();
  }

#pragma unroll
  for (int i = 0; i < 4; i++) {
#pragma unroll
    for (int r = 0; r < 4; r++) {
      int row = m0 + wm + i * 16 + quad * 4 + r;
      if (row < m_end) {
#pragma unroll
        for (int j = 0; j < 4; j++) {
          int col = n0 + wn + j * 16 + l15;
          out[(size_t)row * kHID + col] = acc[i][j][r];
        }
      }
    }
  }
}

extern "C" void kernel_launch(void* const* d_in, const int* in_sizes, int n_in,
                              void* d_out, int out_size, void* d_ws, size_t ws_size,
                              hipStream_t stream) {
  const float* x = (const float*)d_in[0];
  const float* probs = (const float*)d_in[1];
  const float* wg = (const float*)d_in[2];
  const float* wu = (const float*)d_in[3];
  const float* wd = (const float*)d_in[4];
  const int* tpe = (const int*)d_in[5];
  float* out = (float*)d_out;

  // ws layout (u16 elements): Xb | Wg_t | Wu_t | Wd_t | H  (~186 MB total)
  u16* ws = (u16*)d_ws;
  u16* Xb = ws;
  u16* Wgt = Xb + (size_t)kTOT * kHID;             // 16,777,216
  u16* Wut = Wgt + (size_t)kE * kINTER * kHID;     // +23,068,672
  u16* Wdt = Wut + (size_t)kE * kINTER * kHID;
  u16* H = Wdt + (size_t)kE * kHID * kINTER;

  conv_bf16<<<(kTOT * kHID) / (256 * 8), 256, 0, stream>>>(x, Xb);
  // w_gate/w_up: [E][HID][INTER] -> [E][INTER][HID]
  transp_bf16<<<dim3(kINTER / 64, kHID / 64, kE), 256, 0, stream>>>(wg, Wgt, kHID, kINTER);
  transp_bf16<<<dim3(kINTER / 64, kHID / 64, kE), 256, 0, stream>>>(wu, Wut, kHID, kINTER);
  // w_down: [E][INTER][HID] -> [E][HID][INTER]
  transp_bf16<<<dim3(kHID / 64, kINTER / 64, kE), 256, 0, stream>>>(wd, Wdt, kINTER, kHID);

  // max m-tiles: 64 full + up to 7 partials; extra blocks early-exit
  gemm1<<<dim3(kINTER / 128, 72), 256, 0, stream>>>(Xb, Wgt, Wut, probs, tpe, H);
  gemm2<<<dim3(kHID / 128, 72), 256, 0, stream>>>(H, Wdt, tpe, out);
}